// Round 10
// baseline (167.760 us; speedup 1.0000x reference)
//
#include <hip/hip_runtime.h>

// SIRD RK4, round 10: issue-slot trim. Established (R1-R9): lone-wave issue
// cadence = 4.0 cyc/VALU-inst, hard, independent of ILP/dep-depth; packed
// VOP3P issues at half rate; substep count already minimal (h=1; h=2 over
// error threshold). Floor = 2047 serial steps x ~25 slots x 4 cyc ~ 85-90 us
// kernel + ~55 us fixed harness overhead.
// This round: store TWO tsteps per global_store_dwordx4 (even-t float4 is
// 16B aligned), pair-unrolled loop, minimal temps.
//
// State (sigma, I), sigma = c*S: d(sigma) = -c*(sigma*I), dI = fma(-gm,I,m).
// D from RK4-preserved invariant: D = fma(nkc, sigma, fma(nk, I, kDN)).

#define N_POP 1.0e7f
#define T_PTS 2048

__global__ __launch_bounds__(64, 1) void sird_kernel(const float* __restrict__ alpha,
                                                     float* __restrict__ out) {
    const int s = blockIdx.x * blockDim.x + threadIdx.x;

    const float beta  = alpha[s * 3 + 0];
    const float gamma = alpha[s * 3 + 1];
    const float mu    = alpha[s * 3 + 2];

    const float c    = beta * (1.0f / N_POP);
    const float gm   = gamma + mu;
    const float ngm  = -gm;
    const float h2   = 0.5f;              // h/2, h = 1
    const float nch2 = -0.5f * c;         // -c*h/2
    const float nch  = -c;                // -c*h
    const float w    = 1.0f / 6.0f;
    const float nwc  = -c * (1.0f / 6.0f);
    const float kD   = mu / gm;           // gamma,mu > 0 a.s.
    const float kDN  = kD * (float)N_POP;
    const float nkc  = -kD / c;
    const float nk   = -kD;

    float sg = c * (N_POP - 1.0f);        // sigma = c*S
    float I  = 1.0f;

    float2* __restrict__ orow = (float2*)out + (size_t)s * T_PTS;
    orow[0] = make_float2(1.0f, 0.0f);

#define RK4_CORE(IOUT, DOUT)                                                 \
    do {                                                                     \
        const float m1 = sg * I;                                             \
        const float g1 = __builtin_fmaf(ngm, I, m1);                         \
        const float s2 = __builtin_fmaf(nch2, m1, sg);                       \
        const float i2 = __builtin_fmaf(h2, g1, I);                          \
        const float m2 = s2 * i2;                                            \
        const float g2 = __builtin_fmaf(ngm, i2, m2);                        \
        const float s3 = __builtin_fmaf(nch2, m2, sg);                       \
        const float i3 = __builtin_fmaf(h2, g2, I);                          \
        const float m3 = s3 * i3;                                            \
        const float g3 = __builtin_fmaf(ngm, i3, m3);                        \
        const float s4 = __builtin_fmaf(nch, m3, sg);                        \
        const float i4 = I + g3;                                             \
        const float m4 = s4 * i4;                                            \
        const float g4 = __builtin_fmaf(ngm, i4, m4);                        \
        float tm = __builtin_fmaf(2.0f, m2, m1);                             \
        tm = __builtin_fmaf(2.0f, m3, tm);                                   \
        sg = __builtin_fmaf(nwc, m4, __builtin_fmaf(nwc, tm, sg));           \
        float tg = __builtin_fmaf(2.0f, g2, g1);                             \
        tg = __builtin_fmaf(2.0f, g3, tg);                                   \
        I = __builtin_fmaf(w, g4, __builtin_fmaf(w, tg, I));                 \
        (IOUT) = I;                                                          \
        (DOUT) = __builtin_fmaf(nkc, sg, __builtin_fmaf(nk, I, kDN));        \
    } while (0)

    // tstep 1: single float2 store (odd index)
    {
        float Iv, Dv;
        RK4_CORE(Iv, Dv);
        orow[1] = make_float2(Iv, Dv);
    }
    // tsteps 2..2047 as 1023 pairs; even t -> 16B-aligned float4 store
    float4* __restrict__ orow4 = (float4*)(orow + 2);
#pragma unroll 3
    for (int p = 0; p < (T_PTS - 2) / 2; ++p) {
        float4 o;
        RK4_CORE(o.x, o.y);
        RK4_CORE(o.z, o.w);
        orow4[p] = o;
    }
#undef RK4_CORE
}

extern "C" void kernel_launch(void* const* d_in, const int* in_sizes, int n_in,
                              void* d_out, int out_size, void* d_ws, size_t ws_size,
                              hipStream_t stream) {
    const float* alpha = (const float*)d_in[0];
    float* out = (float*)d_out;
    sird_kernel<<<dim3(T_PTS / 64), dim3(64), 0, stream>>>(alpha, out);
}

// Round 11
// 156.124 us; speedup vs baseline: 1.0745x; 1.0745x over previous
//
#include <hip/hip_runtime.h>

// SIRD RK4, round 11: producer/consumer wave split.
// Established (R1-R10): lone-wave issue cadence = 4.0 cyc/VALU-slot, hard,
// ILP/dep-depth independent; packed VOP3P half-rate; h=1 minimal. R9's 31
// slots/tstep = 22 irreducible RK4 + ~9 epilogue (D fmas, store packing,
// store, addr). Fix: move the epilogue to a SECOND wave (different SIMD,
// fully concurrent per m114). Producer: RK4 + one ds_write_b64/tstep
// (immediate offsets) = ~23 slots. Consumer: ds_read + D-invariant fmas +
// store = ~6 slots, always waiting at the barrier. One __syncthreads per
// 32-tstep segment, double-buffered LDS.
//
// State (sigma, I), sigma = c*S: d(sigma) = -c*(sigma*I), dI = fma(-gm,I,m).
// D from RK4-preserved invariant: D = fma(-kD/c, sigma, fma(-kD, I, kD*N)).
// Slot t of a segment holds the PRE-step state at tstep t (t=0 = initial),
// so the consumer emits all 2048 rows uniformly, including orow[0].

#define N_POP 1.0e7f
#define T_PTS 2048
#define KSEG 32
#define NSEG (T_PTS / KSEG)   // 64 segments

__global__ __launch_bounds__(128, 1) void sird_kernel(const float* __restrict__ alpha,
                                                      float* __restrict__ out) {
    const int lane = threadIdx.x & 63;
    const int wave = threadIdx.x >> 6;        // 0 = producer, 1 = consumer
    const int s = blockIdx.x * 64 + lane;     // scenario (same for both waves)

    __shared__ float2 buf[2][KSEG][64];       // [buffer][k][lane] = 32 KiB

    const float beta  = alpha[s * 3 + 0];
    const float gamma = alpha[s * 3 + 1];
    const float mu    = alpha[s * 3 + 2];

    const float c    = beta * (1.0f / N_POP);
    const float gm   = gamma + mu;
    const float ngm  = -gm;
    const float h2   = 0.5f;                  // h/2, h = 1
    const float nch2 = -0.5f * c;             // -c*h/2
    const float nch  = -c;                    // -c*h
    const float w    = 1.0f / 6.0f;
    const float nwc  = -c * (1.0f / 6.0f);
    const float kD   = mu / gm;               // gamma,mu > 0 a.s. (validated R9/R10)
    const float kDN  = kD * (float)N_POP;
    const float nkc  = -kD / c;
    const float nk   = -kD;

    float sg = c * (N_POP - 1.0f);            // sigma = c*S
    float I  = 1.0f;

    float2* __restrict__ orow = (float2*)out + (size_t)s * T_PTS;

    for (int seg = 0; seg <= NSEG; ++seg) {
        if (wave == 0) {
            if (seg < NSEG) {
                float2* bp = &buf[seg & 1][0][lane];
#pragma unroll
                for (int k = 0; k < KSEG; ++k) {
                    bp[k * 64] = make_float2(sg, I);     // state at t = seg*KSEG + k
                    // RK4 step h=1 (22 VALU slots)
                    const float m1 = sg * I;
                    const float g1 = __builtin_fmaf(ngm, I, m1);
                    const float s2 = __builtin_fmaf(nch2, m1, sg);
                    const float i2 = __builtin_fmaf(h2, g1, I);
                    const float m2 = s2 * i2;
                    const float g2 = __builtin_fmaf(ngm, i2, m2);
                    const float s3 = __builtin_fmaf(nch2, m2, sg);
                    const float i3 = __builtin_fmaf(h2, g2, I);
                    const float m3 = s3 * i3;
                    const float g3 = __builtin_fmaf(ngm, i3, m3);
                    const float s4 = __builtin_fmaf(nch, m3, sg);
                    const float i4 = I + g3;
                    const float m4 = s4 * i4;
                    const float g4 = __builtin_fmaf(ngm, i4, m4);
                    float tm = __builtin_fmaf(2.0f, m2, m1);
                    tm = __builtin_fmaf(2.0f, m3, tm);
                    sg = __builtin_fmaf(nwc, m4, __builtin_fmaf(nwc, tm, sg));
                    float tg = __builtin_fmaf(2.0f, g2, g1);
                    tg = __builtin_fmaf(2.0f, g3, tg);
                    I = __builtin_fmaf(w, g4, __builtin_fmaf(w, tg, I));
                }
            }
        } else {
            if (seg >= 1) {
                const float2* qp = &buf[(seg - 1) & 1][0][lane];
                float2* op = orow + (size_t)(seg - 1) * KSEG;
#pragma unroll
                for (int k = 0; k < KSEG; ++k) {
                    const float2 v = qp[k * 64];         // (sigma_t, I_t)
                    const float Dv = __builtin_fmaf(nkc, v.x,
                                     __builtin_fmaf(nk, v.y, kDN));
                    op[k] = make_float2(v.y, Dv);
                }
            }
        }
        __syncthreads();
    }
}

extern "C" void kernel_launch(void* const* d_in, const int* in_sizes, int n_in,
                              void* d_out, int out_size, void* d_ws, size_t ws_size,
                              hipStream_t stream) {
    const float* alpha = (const float*)d_in[0];
    float* out = (float*)d_out;
    // 2048 scenarios / 64 lanes = 32 blocks of 2 waves (producer + consumer).
    sird_kernel<<<dim3(T_PTS / 64), dim3(128), 0, stream>>>(alpha, out);
}